// Round 1
// baseline (311.668 us; speedup 1.0000x reference)
//
#include <hip/hip_runtime.h>

// fp16 compute throughout (fp16 MFMA = bf16 rate on gfx950, 8x lower rounding error).
typedef _Float16 f16;
typedef __attribute__((ext_vector_type(8))) _Float16 f16x8;
typedef __attribute__((ext_vector_type(4))) _Float16 f16x4;
typedef __attribute__((ext_vector_type(4))) float   f32x4;

#define LOG2E 1.4426950408889634f

typedef unsigned int u32;
typedef __attribute__((address_space(1))) const u32 gu32;
typedef __attribute__((address_space(3))) u32 lu32;

// async global->LDS, 16B per lane; LDS dest = wave-uniform base + lane*16
__device__ inline void gll16(const void* g, void* l) {
  __builtin_amdgcn_global_load_lds((gu32*)g, (lu32*)l, 16, 0, 0);
}

// ---------------- f32 -> f16 elementwise convert (x) ----------------
__global__ void cvt_f32_f16(const float* __restrict__ in, f16* __restrict__ out, int n4) {
  int i = blockIdx.x * blockDim.x + threadIdx.x;
  if (i < n4) {
    float4 v = ((const float4*)in)[i];
    f16x4 r = { (f16)v.x, (f16)v.y, (f16)v.z, (f16)v.w };
    ((f16x4*)out)[i] = r;
  }
}

// ---------------- f32 -> f16 transpose (weights): dst[c][r] = src[r][c] ----------------
// src: H x W (row-major f32); dst: W x H (row-major f16). H,W multiples of 32.
__global__ void transpose_cvt(const float* __restrict__ src, f16* __restrict__ dst, int H, int W) {
  __shared__ float tile[32][33];
  int c0 = blockIdx.x * 32, r0 = blockIdx.y * 32;
  int tx = threadIdx.x, ty = threadIdx.y;   // block (32,8)
  for (int i = 0; i < 4; i++)
    tile[ty + i * 8][tx] = src[(size_t)(r0 + ty + i * 8) * W + c0 + tx];
  __syncthreads();
  for (int i = 0; i < 4; i++)
    dst[(size_t)(c0 + ty + i * 8) * H + r0 + tx] = (f16)tile[tx][ty + i * 8];
}

// ---------------- NT GEMM: C[M,N] = A(M,K) * Bt(N,K)^T, fp16 in, f32 acc ----------------
// 128x128 block tile, 4 waves (2x2), each wave 64x64 = 4x4 MFMA tiles, BK=32.
// EPI 0: scatter into q (scaled 1/8), k, v^T fp16 buffers.  EPI 1: out = C + bo (f32).
template<int EPI>
__global__ __launch_bounds__(256) void gemm_nt(
    const f16* __restrict__ A, const f16* __restrict__ Bt, int K,
    f16* __restrict__ qb, f16* __restrict__ kb, f16* __restrict__ vtb,
    const float* __restrict__ bo, float* __restrict__ outf) {
  __shared__ f16 As[128 * 32];
  __shared__ f16 Bs[128 * 32];
  int tid = threadIdx.x;
  int wave = tid >> 6, lane = tid & 63, quad = lane >> 4, l16 = lane & 15;
  int m0 = blockIdx.y * 128, n0 = blockIdx.x * 128;
  int wr = (wave >> 1) * 64, wc = (wave & 1) * 64;

  f32x4 acc[4][4] = {};

  const f16* Ag = A + (size_t)(m0 + wave * 32 + (lane >> 2)) * K + (lane & 3) * 8;
  const f16* Bg = Bt + (size_t)(n0 + wave * 32 + (lane >> 2)) * K + (lane & 3) * 8;
  f16* Asw = As + wave * 1024;   // 2048 bytes per wave region
  f16* Bsw = Bs + wave * 1024;

  for (int k0 = 0; k0 < K; k0 += 32) {
    gll16(Ag + k0, Asw);
    gll16(Ag + (size_t)16 * K + k0, Asw + 512);
    gll16(Bg + k0, Bsw);
    gll16(Bg + (size_t)16 * K + k0, Bsw + 512);
    __syncthreads();
    f16x8 af[4], bf[4];
    for (int mt = 0; mt < 4; mt++) af[mt] = *(const f16x8*)&As[(wr + mt * 16 + l16) * 32 + quad * 8];
    for (int nt = 0; nt < 4; nt++) bf[nt] = *(const f16x8*)&Bs[(wc + nt * 16 + l16) * 32 + quad * 8];
    for (int mt = 0; mt < 4; mt++)
      for (int nt = 0; nt < 4; nt++)
        acc[mt][nt] = __builtin_amdgcn_mfma_f32_16x16x32_f16(af[mt], bf[nt], acc[mt][nt], 0, 0, 0);
    __syncthreads();
  }

  // epilogue; C/D layout: row = quad*4+reg, col = l16 (within 16x16 tile)
  for (int mt = 0; mt < 4; mt++)
    for (int nt = 0; nt < 4; nt++)
      for (int r = 0; r < 4; r++) {
        int row = m0 + wr + mt * 16 + quad * 4 + r;
        int col = n0 + wc + nt * 16 + l16;
        float v = acc[mt][nt][r];
        if (EPI == 0) {
          int b = row >> 11, n = row & 2047;
          if (col < 1024) {
            qb[(((size_t)b * 16 + (col >> 6)) * 2048 + n) * 64 + (col & 63)] = (f16)(v * 0.125f);
          } else if (col < 2048) {
            int c = col - 1024;
            kb[(((size_t)b * 16 + (c >> 6)) * 2048 + n) * 64 + (c & 63)] = (f16)v;
          } else {
            int c = col - 2048;
            vtb[(((size_t)b * 16 + (c >> 6)) * 64 + (c & 63)) * 2048 + n] = (f16)v;
          }
        } else {
          outf[(size_t)row * 1024 + col] = v + bo[col];
        }
      }
}

// ---------------- fused causal attention, online softmax ----------------
// NOTE: gm (softmax shift) = row max of UNMASKED scores (reference semantics), so we
// iterate ALL kv blocks for the max; masked entries contribute 0 to p/l/acc.
// grid (N/128, B*H); 4 waves; wave owns 32 q rows (2 m-tiles); KV block = 64.
__global__ __launch_bounds__(256) void attn(
    const f16* __restrict__ qb, const f16* __restrict__ kb,
    const f16* __restrict__ vtb, f16* __restrict__ ob) {
  __shared__ f16 Ks[64 * 64];        // [j][d]
  __shared__ f16 Vs[64 * 64];        // [d][j]  (v stored transposed -> contiguous B-frags)
  __shared__ f16 Ps[4][32 * 64];     // per-wave P round-trip (C-layout -> A-layout)
  int tid = threadIdx.x, wave = tid >> 6, lane = tid & 63, quad = lane >> 4, l16 = lane & 15;
  int bh = blockIdx.y, qi0 = blockIdx.x * 128;
  int b = bh >> 4, h = bh & 15;
  const f16* Q  = qb  + (size_t)bh * 2048 * 64;
  const f16* Kg = kb  + (size_t)bh * 2048 * 64;
  const f16* Vg = vtb + (size_t)bh * 64 * 2048;
  int wq0 = qi0 + wave * 32;

  f16x8 qf[2][2];
  for (int mt = 0; mt < 2; mt++)
    for (int ks = 0; ks < 2; ks++)
      qf[mt][ks] = *(const f16x8*)&Q[(size_t)(wq0 + mt * 16 + l16) * 64 + ks * 32 + quad * 8];

  f32x4 acc[2][4] = {};
  float mrow[2][4], lrow[2][4];
  for (int mt = 0; mt < 2; mt++)
    for (int r = 0; r < 4; r++) { mrow[mt][r] = -1e30f; lrow[mt][r] = 0.f; }

  for (int j0 = 0; j0 < 2048; j0 += 64) {
    // stage K block: 8KB contiguous in global
    const char* kg = (const char*)(Kg + (size_t)j0 * 64);
    gll16(kg + wave * 2048 + lane * 16, (char*)Ks + wave * 2048);
    gll16(kg + wave * 2048 + 1024 + lane * 16, (char*)Ks + wave * 2048 + 1024);
    // stage V^T block: 64 rows(d) x 128B
    {
      int d0 = wave * 16;
      gll16((const char*)(Vg + (size_t)(d0 + (lane >> 3)) * 2048 + j0) + (lane & 7) * 16,
            (char*)Vs + d0 * 128);
      gll16((const char*)(Vg + (size_t)(d0 + 8 + (lane >> 3)) * 2048 + j0) + (lane & 7) * 16,
            (char*)Vs + (d0 + 8) * 128);
    }
    __syncthreads();

    // S = Q K^T  (scale already folded into q)
    f16x8 kf[4][2];
    for (int nt = 0; nt < 4; nt++)
      for (int ks = 0; ks < 2; ks++)
        kf[nt][ks] = *(const f16x8*)&Ks[(nt * 16 + l16) * 64 + ks * 32 + quad * 8];
    f32x4 s[2][4];
    for (int mt = 0; mt < 2; mt++)
      for (int nt = 0; nt < 4; nt++) {
        f32x4 z = {0.f, 0.f, 0.f, 0.f};
        z = __builtin_amdgcn_mfma_f32_16x16x32_f16(qf[mt][0], kf[nt][0], z, 0, 0, 0);
        z = __builtin_amdgcn_mfma_f32_16x16x32_f16(qf[mt][1], kf[nt][1], z, 0, 0, 0);
        s[mt][nt] = z;
      }

    bool anyP = (j0 <= wq0 + 31);   // wave-uniform

    for (int mt = 0; mt < 2; mt++) {
      // row max over UNMASKED scores (gm semantics)
      float rmax[4];
      for (int r = 0; r < 4; r++) {
        float v = fmaxf(fmaxf(s[mt][0][r], s[mt][1][r]), fmaxf(s[mt][2][r], s[mt][3][r]));
        v = fmaxf(v, __shfl_xor(v, 1));
        v = fmaxf(v, __shfl_xor(v, 2));
        v = fmaxf(v, __shfl_xor(v, 4));
        v = fmaxf(v, __shfl_xor(v, 8));
        rmax[r] = v;
      }
      float alpha[4];
      for (int r = 0; r < 4; r++) {
        float mn = fmaxf(mrow[mt][r], rmax[r]);
        alpha[r] = exp2f((mrow[mt][r] - mn) * LOG2E);
        mrow[mt][r] = mn;
        lrow[mt][r] *= alpha[r];
      }
      for (int nt = 0; nt < 4; nt++)
        for (int r = 0; r < 4; r++) acc[mt][nt][r] *= alpha[r];

      if (anyP) {
        int irow = wq0 + mt * 16 + quad * 4;
        float psum[4] = {0.f, 0.f, 0.f, 0.f};
        for (int nt = 0; nt < 4; nt++) {
          int jc = j0 + nt * 16 + l16;
          for (int r = 0; r < 4; r++) {
            float p = (jc <= irow + r) ? exp2f((s[mt][nt][r] - mrow[mt][r]) * LOG2E) : 0.f;
            psum[r] += p;
            Ps[wave][(mt * 16 + quad * 4 + r) * 64 + nt * 16 + l16] = (f16)p;
          }
        }
        for (int r = 0; r < 4; r++) {
          float v = psum[r];
          v += __shfl_xor(v, 1); v += __shfl_xor(v, 2);
          v += __shfl_xor(v, 4); v += __shfl_xor(v, 8);
          lrow[mt][r] += v;
        }
      }
    }

    if (anyP) {
      f16x8 vf[4][2];
      for (int nt = 0; nt < 4; nt++)
        for (int ks = 0; ks < 2; ks++)
          vf[nt][ks] = *(const f16x8*)&Vs[(nt * 16 + l16) * 64 + ks * 32 + quad * 8];
      for (int mt = 0; mt < 2; mt++)
        for (int ks = 0; ks < 2; ks++) {
          f16x8 pf = *(const f16x8*)&Ps[wave][(mt * 16 + l16) * 64 + ks * 32 + quad * 8];
          for (int nt = 0; nt < 4; nt++)
            acc[mt][nt] = __builtin_amdgcn_mfma_f32_16x16x32_f16(pf, vf[nt][ks], acc[mt][nt], 0, 0, 0);
        }
    }
    __syncthreads();
  }

  // out = acc / (l + eps); write to (b, n, h*64+d) fp16
  for (int mt = 0; mt < 2; mt++) {
    float inv[4];
    for (int r = 0; r < 4; r++) inv[r] = 1.f / (lrow[mt][r] + 1e-8f);
    for (int nt = 0; nt < 4; nt++)
      for (int r = 0; r < 4; r++) {
        int n = wq0 + mt * 16 + quad * 4 + r;
        ob[((size_t)b * 2048 + n) * 1024 + h * 64 + nt * 16 + l16] = (f16)(acc[mt][nt][r] * inv[r]);
      }
  }
}

extern "C" void kernel_launch(void* const* d_in, const int* in_sizes, int n_in,
                              void* d_out, int out_size, void* d_ws, size_t ws_size,
                              hipStream_t stream) {
  const float* x   = (const float*)d_in[0];   // (2,2048,1024)
  const float* Wq  = (const float*)d_in[1];   // (1024,1024)
  const float* Wkv = (const float*)d_in[2];   // (1024,2048)
  const float* Wo  = (const float*)d_in[3];   // (1024,1024)
  const float* bo  = (const float*)d_in[4];   // (1024,)
  float* out = (float*)d_out;                 // (2,2048,1024) f32

  char* ws = (char*)d_ws;
  f16* xb    = (f16*)ws;  ws += (size_t)4096 * 1024 * 2;
  f16* WqkvT = (f16*)ws;  ws += (size_t)3072 * 1024 * 2;
  f16* WoT   = (f16*)ws;  ws += (size_t)1024 * 1024 * 2;
  f16* qb    = (f16*)ws;  ws += (size_t)32 * 2048 * 64 * 2;
  f16* kb    = (f16*)ws;  ws += (size_t)32 * 2048 * 64 * 2;
  f16* vtb   = (f16*)ws;  ws += (size_t)32 * 64 * 2048 * 2;
  f16* ob    = xb;  // xb dead after GEMM1; reuse for attention output (8MB)

  cvt_f32_f16<<<dim3(4096), 256, 0, stream>>>(x, xb, 4096 * 1024 / 4);
  transpose_cvt<<<dim3(32, 32), dim3(32, 8), 0, stream>>>(Wq, WqkvT, 1024, 1024);
  transpose_cvt<<<dim3(64, 32), dim3(32, 8), 0, stream>>>(Wkv, WqkvT + (size_t)1024 * 1024, 1024, 2048);
  transpose_cvt<<<dim3(32, 32), dim3(32, 8), 0, stream>>>(Wo, WoT, 1024, 1024);

  gemm_nt<0><<<dim3(24, 32), 256, 0, stream>>>(xb, WqkvT, 1024, qb, kb, vtb, nullptr, nullptr);
  attn<<<dim3(16, 32), 256, 0, stream>>>(qb, kb, vtb, ob);
  gemm_nt<1><<<dim3(8, 32), 256, 0, stream>>>(ob, WoT, 1024, nullptr, nullptr, nullptr, bo, out);
}

// Round 2
// 251.467 us; speedup vs baseline: 1.2394x; 1.2394x over previous
//
#include <hip/hip_runtime.h>

// fp16 compute throughout (fp16 MFMA = bf16 rate on gfx950, 8x lower rounding error).
typedef _Float16 f16;
typedef __attribute__((ext_vector_type(8))) _Float16 f16x8;
typedef __attribute__((ext_vector_type(4))) _Float16 f16x4;
typedef __attribute__((ext_vector_type(4))) float   f32x4;

typedef unsigned int u32;
typedef __attribute__((address_space(1))) const u32 gu32;
typedef __attribute__((address_space(3))) u32 lu32;

// async global->LDS, 16B per lane; LDS dest = wave-uniform base + lane*16
__device__ inline void gll16(const void* g, void* l) {
  __builtin_amdgcn_global_load_lds((gu32*)g, (lu32*)l, 16, 0, 0);
}

// ---------------- f32 -> f16 elementwise convert (x) ----------------
__global__ void cvt_f32_f16(const float* __restrict__ in, f16* __restrict__ out, int n4) {
  int i = blockIdx.x * blockDim.x + threadIdx.x;
  if (i < n4) {
    float4 v = ((const float4*)in)[i];
    f16x4 r = { (f16)v.x, (f16)v.y, (f16)v.z, (f16)v.w };
    ((f16x4*)out)[i] = r;
  }
}

// ---------------- f32 -> f16 transpose (weights): dst[c][r] = src[r][c] ----------------
__global__ void transpose_cvt(const float* __restrict__ src, f16* __restrict__ dst, int H, int W) {
  __shared__ float tile[32][33];
  int c0 = blockIdx.x * 32, r0 = blockIdx.y * 32;
  int tx = threadIdx.x, ty = threadIdx.y;   // block (32,8)
  for (int i = 0; i < 4; i++)
    tile[ty + i * 8][tx] = src[(size_t)(r0 + ty + i * 8) * W + c0 + tx];
  __syncthreads();
  for (int i = 0; i < 4; i++)
    dst[(size_t)(c0 + ty + i * 8) * H + r0 + tx] = (f16)tile[tx][ty + i * 8];
}

// ---------------- NT GEMM: C[M,N] = A(M,K) * Bt(N,K)^T, fp16 in, f32 acc ----------------
template<int EPI>
__global__ __launch_bounds__(256) void gemm_nt(
    const f16* __restrict__ A, const f16* __restrict__ Bt, int K,
    f16* __restrict__ qb, f16* __restrict__ kb, f16* __restrict__ vtb,
    const float* __restrict__ bo, float* __restrict__ outf) {
  __shared__ f16 As[128 * 32];
  __shared__ f16 Bs[128 * 32];
  int tid = threadIdx.x;
  int wave = tid >> 6, lane = tid & 63, quad = lane >> 4, l16 = lane & 15;
  int m0 = blockIdx.y * 128, n0 = blockIdx.x * 128;
  int wr = (wave >> 1) * 64, wc = (wave & 1) * 64;

  f32x4 acc[4][4] = {};

  const f16* Ag = A + (size_t)(m0 + wave * 32 + (lane >> 2)) * K + (lane & 3) * 8;
  const f16* Bg = Bt + (size_t)(n0 + wave * 32 + (lane >> 2)) * K + (lane & 3) * 8;
  f16* Asw = As + wave * 1024;
  f16* Bsw = Bs + wave * 1024;

  for (int k0 = 0; k0 < K; k0 += 32) {
    gll16(Ag + k0, Asw);
    gll16(Ag + (size_t)16 * K + k0, Asw + 512);
    gll16(Bg + k0, Bsw);
    gll16(Bg + (size_t)16 * K + k0, Bsw + 512);
    __syncthreads();
    f16x8 af[4], bf[4];
    for (int mt = 0; mt < 4; mt++) af[mt] = *(const f16x8*)&As[(wr + mt * 16 + l16) * 32 + quad * 8];
    for (int nt = 0; nt < 4; nt++) bf[nt] = *(const f16x8*)&Bs[(wc + nt * 16 + l16) * 32 + quad * 8];
    for (int mt = 0; mt < 4; mt++)
      for (int nt = 0; nt < 4; nt++)
        acc[mt][nt] = __builtin_amdgcn_mfma_f32_16x16x32_f16(af[mt], bf[nt], acc[mt][nt], 0, 0, 0);
    __syncthreads();
  }

  // epilogue; C/D layout: row = quad*4+reg, col = l16 (within 16x16 tile)
  for (int mt = 0; mt < 4; mt++)
    for (int nt = 0; nt < 4; nt++)
      for (int r = 0; r < 4; r++) {
        int row = m0 + wr + mt * 16 + quad * 4 + r;
        int col = n0 + wc + nt * 16 + l16;
        float v = acc[mt][nt][r];
        if (EPI == 0) {
          int b = row >> 11, n = row & 2047;
          if (col < 1024) {
            // fold attention scale AND log2(e): softmax runs in log2 domain
            qb[(((size_t)b * 16 + (col >> 6)) * 2048 + n) * 64 + (col & 63)] =
                (f16)(v * 0.1803368801111137f);  // 0.125 * log2(e)
          } else if (col < 2048) {
            int c = col - 1024;
            kb[(((size_t)b * 16 + (c >> 6)) * 2048 + n) * 64 + (c & 63)] = (f16)v;
          } else {
            int c = col - 2048;
            vtb[(((size_t)b * 16 + (c >> 6)) * 64 + (c & 63)) * 2048 + n] = (f16)v;
          }
        } else {
          outf[(size_t)row * 1024 + col] = v + bo[col];
        }
      }
}

// ---------------- fused causal attention, causal-only online softmax ----------------
// gm (reference's unmasked row-max) is only a softmax shift; it cancels except via
// eps=1e-8, and eps/sum_p <= ~3e-5 for this data -> causal-only max is equivalent.
// Softmax in log2 domain (log2e folded into q at GEMM1 epilogue).
// 512 blocks: tile t costs 2t+2 iters; blocks i and i+256 share a CU (round-robin
// dispatch model), so second half gets tile 15-t -> per-CU work uniform (34 iters).
__global__ __launch_bounds__(256) void attn(
    const f16* __restrict__ qb, const f16* __restrict__ kb,
    const f16* __restrict__ vtb, f16* __restrict__ ob) {
  __shared__ f16 Ks[64 * 64];        // [j][d]
  __shared__ f16 Vs[64 * 64];        // [d][j]
  __shared__ f16 Ps[4][32 * 72];     // per-wave P round-trip, stride 72 (pad: kills 8-way conflict)
  int tid = threadIdx.x, wave = tid >> 6, lane = tid & 63, quad = lane >> 4, l16 = lane & 15;

  int bx = blockIdx.x;               // gridDim = 512
  int half = bx >> 8, r9 = bx & 255;
  int t = half ? 15 - (r9 & 15) : (r9 & 15);
  int bh = (half << 4) + (r9 >> 4);
  int qi0 = t * 128;
  int b = bh >> 4, h = bh & 15;

  const f16* Q  = qb  + (size_t)bh * 2048 * 64;
  const f16* Kg = kb  + (size_t)bh * 2048 * 64;
  const f16* Vg = vtb + (size_t)bh * 64 * 2048;
  int wq0 = qi0 + wave * 32;

  f16x8 qf[2][2];
  for (int mt = 0; mt < 2; mt++)
    for (int ks = 0; ks < 2; ks++)
      qf[mt][ks] = *(const f16x8*)&Q[(size_t)(wq0 + mt * 16 + l16) * 64 + ks * 32 + quad * 8];

  f32x4 acc[2][4] = {};
  float mrow[2][4], lrow[2][4];
  for (int mt = 0; mt < 2; mt++)
    for (int r = 0; r < 4; r++) { mrow[mt][r] = -1e30f; lrow[mt][r] = 0.f; }

  for (int j0 = 0; j0 < qi0 + 128; j0 += 64) {
    // stage K block (8KB contiguous)
    const char* kg = (const char*)(Kg + (size_t)j0 * 64);
    gll16(kg + wave * 2048 + lane * 16, (char*)Ks + wave * 2048);
    gll16(kg + wave * 2048 + 1024 + lane * 16, (char*)Ks + wave * 2048 + 1024);
    // stage V^T block (64 d-rows x 128B)
    {
      int d0 = wave * 16;
      gll16((const char*)(Vg + (size_t)(d0 + (lane >> 3)) * 2048 + j0) + (lane & 7) * 16,
            (char*)Vs + d0 * 128);
      gll16((const char*)(Vg + (size_t)(d0 + 8 + (lane >> 3)) * 2048 + j0) + (lane & 7) * 16,
            (char*)Vs + (d0 + 8) * 128);
    }
    __syncthreads();

    if (j0 <= wq0 + 31) {            // wave has at least one unmasked row here
      f16x8 kf[4][2];
      for (int nt = 0; nt < 4; nt++)
        for (int ks = 0; ks < 2; ks++)
          kf[nt][ks] = *(const f16x8*)&Ks[(nt * 16 + l16) * 64 + ks * 32 + quad * 8];
      f16x8 vf[4][2];
      for (int nt = 0; nt < 4; nt++)
        for (int ks = 0; ks < 2; ks++)
          vf[nt][ks] = *(const f16x8*)&Vs[(nt * 16 + l16) * 64 + ks * 32 + quad * 8];

      for (int mt = 0; mt < 2; mt++) {
        int irow0 = wq0 + mt * 16;
        if (j0 > irow0 + 15) continue;    // dead m-tile (wave-uniform)

        // S = Q K^T (log2 domain; scale folded into q)
        f32x4 s[4];
        for (int nt = 0; nt < 4; nt++) {
          f32x4 z = {0.f, 0.f, 0.f, 0.f};
          z = __builtin_amdgcn_mfma_f32_16x16x32_f16(qf[mt][0], kf[nt][0], z, 0, 0, 0);
          z = __builtin_amdgcn_mfma_f32_16x16x32_f16(qf[mt][1], kf[nt][1], z, 0, 0, 0);
          s[nt] = z;
        }
        bool full = (j0 + 63 <= irow0);   // no masking needed
        if (!full) {
          int irow = irow0 + quad * 4;
          for (int nt = 0; nt < 4; nt++) {
            int jc = j0 + nt * 16 + l16;
            for (int r = 0; r < 4; r++)
              s[nt][r] = (jc <= irow + r) ? s[nt][r] : -1e30f;
          }
        }
        // causal row max
        float rmax[4];
        for (int r = 0; r < 4; r++) {
          float v = fmaxf(fmaxf(s[0][r], s[1][r]), fmaxf(s[2][r], s[3][r]));
          v = fmaxf(v, __shfl_xor(v, 1));
          v = fmaxf(v, __shfl_xor(v, 2));
          v = fmaxf(v, __shfl_xor(v, 4));
          v = fmaxf(v, __shfl_xor(v, 8));
          rmax[r] = v;
        }
        float alpha[4];
        for (int r = 0; r < 4; r++) {
          float mn = fmaxf(mrow[mt][r], rmax[r]);
          alpha[r] = __builtin_amdgcn_exp2f(mrow[mt][r] - mn);
          mrow[mt][r] = mn;
          lrow[mt][r] *= alpha[r];
        }
        for (int nt = 0; nt < 4; nt++)
          for (int r = 0; r < 4; r++) acc[mt][nt][r] *= alpha[r];

        // p = 2^(s - m); masked entries underflow to 0
        float psum[4] = {0.f, 0.f, 0.f, 0.f};
        for (int nt = 0; nt < 4; nt++)
          for (int r = 0; r < 4; r++) {
            float p = __builtin_amdgcn_exp2f(s[nt][r] - mrow[mt][r]);
            psum[r] += p;
            Ps[wave][(mt * 16 + quad * 4 + r) * 72 + nt * 16 + l16] = (f16)p;
          }
        for (int r = 0; r < 4; r++) {
          float v = psum[r];
          v += __shfl_xor(v, 1); v += __shfl_xor(v, 2);
          v += __shfl_xor(v, 4); v += __shfl_xor(v, 8);
          lrow[mt][r] += v;
        }

        // O += P V
        for (int ks = 0; ks < 2; ks++) {
          f16x8 pf = *(const f16x8*)&Ps[wave][(mt * 16 + l16) * 72 + ks * 32 + quad * 8];
          for (int nt = 0; nt < 4; nt++)
            acc[mt][nt] = __builtin_amdgcn_mfma_f32_16x16x32_f16(pf, vf[nt][ks], acc[mt][nt], 0, 0, 0);
        }
      }
    }
    __syncthreads();
  }

  // out = acc / (l + eps); write to (b, n, h*64+d) fp16
  for (int mt = 0; mt < 2; mt++) {
    float inv[4];
    for (int r = 0; r < 4; r++) inv[r] = 1.f / (lrow[mt][r] + 1e-8f);
    for (int nt = 0; nt < 4; nt++)
      for (int r = 0; r < 4; r++) {
        int n = wq0 + mt * 16 + quad * 4 + r;
        ob[((size_t)b * 2048 + n) * 1024 + h * 64 + nt * 16 + l16] = (f16)(acc[mt][nt][r] * inv[r]);
      }
  }
}

extern "C" void kernel_launch(void* const* d_in, const int* in_sizes, int n_in,
                              void* d_out, int out_size, void* d_ws, size_t ws_size,
                              hipStream_t stream) {
  const float* x   = (const float*)d_in[0];   // (2,2048,1024)
  const float* Wq  = (const float*)d_in[1];   // (1024,1024)
  const float* Wkv = (const float*)d_in[2];   // (1024,2048)
  const float* Wo  = (const float*)d_in[3];   // (1024,1024)
  const float* bo  = (const float*)d_in[4];   // (1024,)
  float* out = (float*)d_out;                 // (2,2048,1024) f32

  char* ws = (char*)d_ws;
  f16* xb    = (f16*)ws;  ws += (size_t)4096 * 1024 * 2;
  f16* WqkvT = (f16*)ws;  ws += (size_t)3072 * 1024 * 2;
  f16* WoT   = (f16*)ws;  ws += (size_t)1024 * 1024 * 2;
  f16* qb    = (f16*)ws;  ws += (size_t)32 * 2048 * 64 * 2;
  f16* kb    = (f16*)ws;  ws += (size_t)32 * 2048 * 64 * 2;
  f16* vtb   = (f16*)ws;  ws += (size_t)32 * 64 * 2048 * 2;
  f16* ob    = xb;  // xb dead after GEMM1; reuse

  cvt_f32_f16<<<dim3(4096), 256, 0, stream>>>(x, xb, 4096 * 1024 / 4);
  transpose_cvt<<<dim3(32, 32), dim3(32, 8), 0, stream>>>(Wq, WqkvT, 1024, 1024);
  transpose_cvt<<<dim3(64, 32), dim3(32, 8), 0, stream>>>(Wkv, WqkvT + (size_t)1024 * 1024, 1024, 2048);
  transpose_cvt<<<dim3(32, 32), dim3(32, 8), 0, stream>>>(Wo, WoT, 1024, 1024);

  gemm_nt<0><<<dim3(24, 32), 256, 0, stream>>>(xb, WqkvT, 1024, qb, kb, vtb, nullptr, nullptr);
  attn<<<dim3(512), 256, 0, stream>>>(qb, kb, vtb, ob);
  gemm_nt<1><<<dim3(8, 32), 256, 0, stream>>>(ob, WoT, 1024, nullptr, nullptr, nullptr, bo, out);
}

// Round 3
// 197.321 us; speedup vs baseline: 1.5795x; 1.2744x over previous
//
#include <hip/hip_runtime.h>

// fp16 compute throughout (fp16 MFMA = bf16 rate on gfx950, 8x lower rounding error).
typedef _Float16 f16;
typedef __attribute__((ext_vector_type(8))) _Float16 f16x8;
typedef __attribute__((ext_vector_type(4))) _Float16 f16x4;
typedef __attribute__((ext_vector_type(4))) float   f32x4;

typedef unsigned int u32;
typedef __attribute__((address_space(1))) const u32 gu32;
typedef __attribute__((address_space(3))) u32 lu32;

// async global->LDS, 16B per lane; LDS dest = wave-uniform base + lane*16
__device__ inline void gll16(const void* g, void* l) {
  __builtin_amdgcn_global_load_lds((gu32*)g, (lu32*)l, 16, 0, 0);
}

// ---------------- f32 -> f16 elementwise convert (x) ----------------
__global__ void cvt_f32_f16(const float* __restrict__ in, f16* __restrict__ out, int n4) {
  int i = blockIdx.x * blockDim.x + threadIdx.x;
  if (i < n4) {
    float4 v = ((const float4*)in)[i];
    f16x4 r = { (f16)v.x, (f16)v.y, (f16)v.z, (f16)v.w };
    ((f16x4*)out)[i] = r;
  }
}

// ---------------- fused f32->f16 transpose of all three weight matrices ----------------
__global__ void transpose3(const float* __restrict__ Wq, const float* __restrict__ Wkv,
                           const float* __restrict__ Wo, f16* __restrict__ WqkvT,
                           f16* __restrict__ WoT) {
  __shared__ float tile[32][33];
  int z = blockIdx.z;
  const float* src; f16* dst; int W;
  if (z == 0)      { src = Wq;  dst = WqkvT;                       W = 1024; }
  else if (z == 1) { src = Wkv; dst = WqkvT + (size_t)1024 * 1024; W = 2048; }
  else             { src = Wo;  dst = WoT;                         W = 1024; }
  int c0 = blockIdx.x * 32, r0 = blockIdx.y * 32;
  if (c0 >= W) return;
  int tx = threadIdx.x, ty = threadIdx.y;   // block (32,8)
  for (int i = 0; i < 4; i++)
    tile[ty + i * 8][tx] = src[(size_t)(r0 + ty + i * 8) * W + c0 + tx];
  __syncthreads();
  for (int i = 0; i < 4; i++)
    dst[(size_t)(c0 + ty + i * 8) * 1024 + r0 + tx] = (f16)tile[tx][ty + i * 8];
}

// ---------------- GEMM1: C[M,3072] = A(M,1024) * Bt(3072,1024)^T ----------------
// 128x128 tile, 4 waves 2x2, BK=32, XOR-swizzled LDS (16B chunks: pos = p ^ ((row>>1)&3)).
// Epilogue scatters q (scaled)/k row-major [n][d]; v into blocked tiles [bh][jblk][d][64j].
__global__ __launch_bounds__(256) void gemm1(
    const f16* __restrict__ A, const f16* __restrict__ Bt,
    f16* __restrict__ qb, f16* __restrict__ kb, f16* __restrict__ vtb) {
  const int K = 1024;
  __shared__ f16 As[128 * 32];
  __shared__ f16 Bs[128 * 32];
  int tid = threadIdx.x;
  int wave = tid >> 6, lane = tid & 63, quad = lane >> 4, l16 = lane & 15;
  int m0 = blockIdx.y * 128, n0 = blockIdx.x * 128;
  int wr = (wave >> 1) * 64, wc = (wave & 1) * 64;

  f32x4 acc[4][4] = {};

  int gA = (((lane & 3) ^ ((lane >> 3) & 3))) * 8;   // swizzled source k-chunk (f16 elems)
  const f16* Ag = A  + (size_t)(m0 + wave * 32 + (lane >> 2)) * K + gA;
  const f16* Bg = Bt + (size_t)(n0 + wave * 32 + (lane >> 2)) * K + gA;
  f16* Asw = As + wave * 1024;
  f16* Bsw = Bs + wave * 1024;
  int rsz = (l16 >> 1) & 3;                          // read-side swizzle key

  for (int k0 = 0; k0 < K; k0 += 32) {
    gll16(Ag + k0, Asw);
    gll16(Ag + (size_t)16 * K + k0, Asw + 512);
    gll16(Bg + k0, Bsw);
    gll16(Bg + (size_t)16 * K + k0, Bsw + 512);
    __syncthreads();
    f16x8 af[4], bf[4];
    for (int mt = 0; mt < 4; mt++)
      af[mt] = *(const f16x8*)&As[(wr + mt * 16 + l16) * 32 + ((quad ^ rsz) << 3)];
    for (int nt = 0; nt < 4; nt++)
      bf[nt] = *(const f16x8*)&Bs[(wc + nt * 16 + l16) * 32 + ((quad ^ rsz) << 3)];
    for (int mt = 0; mt < 4; mt++)
      for (int nt = 0; nt < 4; nt++)
        acc[mt][nt] = __builtin_amdgcn_mfma_f32_16x16x32_f16(af[mt], bf[nt], acc[mt][nt], 0, 0, 0);
    __syncthreads();
  }

  // epilogue; C/D layout: row = quad*4+r, col = l16 (within 16x16 tile)
  if (n0 < 2048) {
    for (int mt = 0; mt < 4; mt++)
      for (int nt = 0; nt < 4; nt++)
        for (int r = 0; r < 4; r++) {
          int row = m0 + wr + mt * 16 + quad * 4 + r;
          int col = n0 + wc + nt * 16 + l16;
          float v = acc[mt][nt][r];
          int b = row >> 11, n = row & 2047;
          if (col < 1024) {
            // fold attention scale AND log2(e): softmax runs in log2 domain
            qb[(((size_t)b * 16 + (col >> 6)) * 2048 + n) * 64 + (col & 63)] =
                (f16)(v * 0.1803368801111137f);  // 0.125 * log2(e)
          } else {
            int c = col - 1024;
            kb[(((size_t)b * 16 + (c >> 6)) * 2048 + n) * 64 + (c & 63)] = (f16)v;
          }
        }
  } else {
    // v: blocked [bh][jblk][d][jin], packed f16x4 along n (jin)
    for (int mt = 0; mt < 4; mt++)
      for (int nt = 0; nt < 4; nt++) {
        int rb = m0 + wr + mt * 16 + quad * 4;       // rows rb..rb+3, same b / same 64-block
        int c  = n0 + wc + nt * 16 + l16 - 2048;
        int b = rb >> 11, n = rb & 2047;
        f16x4 pk = { (f16)acc[mt][nt][0], (f16)acc[mt][nt][1],
                     (f16)acc[mt][nt][2], (f16)acc[mt][nt][3] };
        size_t idx = (((size_t)(b * 16 + (c >> 6)) * 32 + (n >> 6)) * 64 + (c & 63)) * 64 + (n & 63);
        *(f16x4*)&vtb[idx] = pk;
      }
  }
}

// ---------------- GEMM2: out[M,1024] = A(M,1024)*Bt(1024,1024)^T + bo ----------------
// 128x64 tile -> 512 blocks = 2/CU (128x128 gave only 1/CU, barrier-exposed).
__global__ __launch_bounds__(256) void gemm2(
    const f16* __restrict__ A, const f16* __restrict__ Bt,
    const float* __restrict__ bo, float* __restrict__ outf) {
  const int K = 1024;
  __shared__ f16 As[128 * 32];
  __shared__ f16 Bs[64 * 32];
  int tid = threadIdx.x;
  int wave = tid >> 6, lane = tid & 63, quad = lane >> 4, l16 = lane & 15;
  int m0 = blockIdx.y * 128, n0 = blockIdx.x * 64;
  int wr = (wave >> 1) * 64, wc = (wave & 1) * 32;

  f32x4 acc[4][2] = {};

  int gA = (((lane & 3) ^ ((lane >> 3) & 3))) * 8;
  const f16* Ag = A  + (size_t)(m0 + wave * 32 + (lane >> 2)) * K + gA;
  const f16* Bg = Bt + (size_t)(n0 + wave * 16 + (lane >> 2)) * K + gA;
  f16* Asw = As + wave * 1024;
  f16* Bsw = Bs + wave * 512;
  int rsz = (l16 >> 1) & 3;

  for (int k0 = 0; k0 < K; k0 += 32) {
    gll16(Ag + k0, Asw);
    gll16(Ag + (size_t)16 * K + k0, Asw + 512);
    gll16(Bg + k0, Bsw);
    __syncthreads();
    f16x8 af[4], bf[2];
    for (int mt = 0; mt < 4; mt++)
      af[mt] = *(const f16x8*)&As[(wr + mt * 16 + l16) * 32 + ((quad ^ rsz) << 3)];
    for (int nt = 0; nt < 2; nt++)
      bf[nt] = *(const f16x8*)&Bs[(wc + nt * 16 + l16) * 32 + ((quad ^ rsz) << 3)];
    for (int mt = 0; mt < 4; mt++)
      for (int nt = 0; nt < 2; nt++)
        acc[mt][nt] = __builtin_amdgcn_mfma_f32_16x16x32_f16(af[mt], bf[nt], acc[mt][nt], 0, 0, 0);
    __syncthreads();
  }

  for (int mt = 0; mt < 4; mt++)
    for (int nt = 0; nt < 2; nt++)
      for (int r = 0; r < 4; r++) {
        int row = m0 + wr + mt * 16 + quad * 4 + r;
        int col = n0 + wc + nt * 16 + l16;
        outf[(size_t)row * 1024 + col] = acc[mt][nt][r] + bo[col];
      }
}

// ---------------- fused causal attention, transposed-S formulation ----------------
// S^T = mfma(kf, qf): lane owns ONE q-row (i=l16), 4 j per quad -> per-lane scalar m/l,
// 2-shuffle reductions, packed P writes. O^T = mfma(vf, pf): acc lane = (d=quad*4+r, i=l16).
// K/V/P LDS XOR-swizzled at 16B chunks (pos = p ^ (row&7)) -> conflict-free frag reads.
// gm (unmasked row-max) is only a softmax shift; cancels except via eps (<=3e-5) -> causal-only.
__global__ __launch_bounds__(256) void attn(
    const f16* __restrict__ qb, const f16* __restrict__ kb,
    const f16* __restrict__ vtb, f16* __restrict__ ob) {
  __shared__ f16 Ks[64 * 64];        // [j][d], swizzled
  __shared__ f16 Vs[64 * 64];        // [d][j], swizzled
  __shared__ f16 Ps[4][16 * 64];     // per-wave [i(16)][j(64)], swizzled
  int tid = threadIdx.x, wave = tid >> 6, lane = tid & 63, quad = lane >> 4, l16 = lane & 15;
  int l7 = l16 & 7;

  int bx = blockIdx.x;               // gridDim = 512; balanced t<->15-t pairing across halves
  int half = bx >> 8, r9 = bx & 255;
  int t = half ? 15 - (r9 & 15) : (r9 & 15);
  int bh = (half << 4) + (r9 >> 4);
  int qi0 = t * 128;
  int b = bh >> 4, h = bh & 15;

  const f16* Q  = qb  + (size_t)bh * 2048 * 64;
  const char* Kg = (const char*)(kb + (size_t)bh * 2048 * 64);
  const char* Vbase = (const char*)(vtb + (size_t)bh * 32 * 4096);
  int wq0 = qi0 + wave * 32;

  f16x8 qf[2][2];
  for (int mt = 0; mt < 2; mt++)
    for (int ks = 0; ks < 2; ks++)
      qf[mt][ks] = *(const f16x8*)&Q[(size_t)(wq0 + mt * 16 + l16) * 64 + ks * 32 + quad * 8];

  f32x4 acc[2][4] = {};
  float mrow[2] = { -1e30f, -1e30f }, lrow[2] = { 0.f, 0.f };

  // staging swizzle (same for every tile): lane covers chunk (row jl, pos lane&7),
  // which must hold global chunk (lane&7)^(jl&7); jl&7 = (lane>>3)&7.
  int sg = ((lane & 7) ^ ((lane >> 3) & 7)) * 16;
  int jl = wave * 16 + (lane >> 3);            // ih=0 row; ih=1 adds 8

  for (int j0 = 0; j0 < qi0 + 128; j0 += 64) {
    const char* kg = Kg + (size_t)j0 * 128;
    const char* vt = Vbase + (size_t)(j0 >> 6) * 8192;
    gll16(kg + (size_t)jl * 128 + sg,        (char*)Ks + wave * 2048);
    gll16(kg + (size_t)(jl + 8) * 128 + sg,  (char*)Ks + wave * 2048 + 1024);
    gll16(vt + (size_t)jl * 128 + sg,        (char*)Vs + wave * 2048);
    gll16(vt + (size_t)(jl + 8) * 128 + sg,  (char*)Vs + wave * 2048 + 1024);
    __syncthreads();

    if (j0 <= wq0 + 31) {
      f16x8 kf[4][2], vf[4][2];
      for (int nt = 0; nt < 4; nt++)
        for (int ks = 0; ks < 2; ks++) {
          int pos = ((ks * 4 + quad) ^ l7) << 3;
          kf[nt][ks] = *(const f16x8*)&Ks[(nt * 16 + l16) * 64 + pos];
          vf[nt][ks] = *(const f16x8*)&Vs[(nt * 16 + l16) * 64 + pos];
        }

      for (int mt = 0; mt < 2; mt++) {
        int im = wq0 + mt * 16;
        if (j0 > im + 15) continue;            // dead m-tile (wave-uniform)
        int i = im + l16;                      // this lane's q-row

        // S^T tiles: lane = (j = j0+nt*16+quad*4+r, i)
        f32x4 st[4];
        for (int nt = 0; nt < 4; nt++) {
          f32x4 z = {0.f, 0.f, 0.f, 0.f};
          z = __builtin_amdgcn_mfma_f32_16x16x32_f16(kf[nt][0], qf[mt][0], z, 0, 0, 0);
          z = __builtin_amdgcn_mfma_f32_16x16x32_f16(kf[nt][1], qf[mt][1], z, 0, 0, 0);
          st[nt] = z;
        }
        bool full = (j0 + 63 <= im);
        if (!full) {
          for (int nt = 0; nt < 4; nt++) {
            int jc = j0 + nt * 16 + quad * 4;
            for (int r = 0; r < 4; r++)
              st[nt][r] = (jc + r <= i) ? st[nt][r] : -1e30f;
          }
        }
        // row max: regs + cross-quad (2 shuffles)
        float v = fmaxf(fmaxf(fmaxf(st[0][0], st[0][1]), fmaxf(st[0][2], st[0][3])),
                        fmaxf(fmaxf(st[1][0], st[1][1]), fmaxf(st[1][2], st[1][3])));
        v = fmaxf(v, fmaxf(fmaxf(fmaxf(st[2][0], st[2][1]), fmaxf(st[2][2], st[2][3])),
                           fmaxf(fmaxf(st[3][0], st[3][1]), fmaxf(st[3][2], st[3][3]))));
        v = fmaxf(v, __shfl_xor(v, 16));
        v = fmaxf(v, __shfl_xor(v, 32));
        float mn = fmaxf(mrow[mt], v);
        float al = __builtin_amdgcn_exp2f(mrow[mt] - mn);
        mrow[mt] = mn;
        lrow[mt] *= al;
        for (int nt = 0; nt < 4; nt++)
          for (int r = 0; r < 4; r++) acc[mt][nt][r] *= al;

        // p = 2^(s-m) (masked underflow to 0); packed write to Ps[i][j] (swizzled)
        float psum = 0.f;
        for (int nt = 0; nt < 4; nt++) {
          f16x4 pk;
          for (int r = 0; r < 4; r++) {
            float p = __builtin_amdgcn_exp2f(st[nt][r] - mn);
            psum += p;
            pk[r] = (f16)p;
          }
          int pos = (nt * 2 + (quad >> 1)) ^ l7;
          *(f16x4*)((char*)&Ps[wave][0] + l16 * 128 + pos * 16 + (quad & 1) * 8) = pk;
        }
        psum += __shfl_xor(psum, 16);
        psum += __shfl_xor(psum, 32);
        lrow[mt] += psum;

        // O^T += V^T P^T
        for (int ks = 0; ks < 2; ks++) {
          f16x8 pf = *(const f16x8*)((char*)&Ps[wave][0] + l16 * 128 + (((ks * 4 + quad) ^ l7) * 16));
          for (int nt = 0; nt < 4; nt++)
            acc[mt][nt] = __builtin_amdgcn_mfma_f32_16x16x32_f16(vf[nt][ks], pf, acc[mt][nt], 0, 0, 0);
        }
      }
    }
    __syncthreads();
  }

  // out = acc / (l + eps); acc lane = (d = nt*16+quad*4+r, i = l16) -> f16x4 along d
  for (int mt = 0; mt < 2; mt++) {
    float inv = 1.f / (lrow[mt] + 1e-8f);
    int n = wq0 + mt * 16 + l16;
    for (int nt = 0; nt < 4; nt++) {
      f16x4 o = { (f16)(acc[mt][nt][0] * inv), (f16)(acc[mt][nt][1] * inv),
                  (f16)(acc[mt][nt][2] * inv), (f16)(acc[mt][nt][3] * inv) };
      *(f16x4*)&ob[((size_t)b * 2048 + n) * 1024 + h * 64 + nt * 16 + quad * 4] = o;
    }
  }
}

extern "C" void kernel_launch(void* const* d_in, const int* in_sizes, int n_in,
                              void* d_out, int out_size, void* d_ws, size_t ws_size,
                              hipStream_t stream) {
  const float* x   = (const float*)d_in[0];   // (2,2048,1024)
  const float* Wq  = (const float*)d_in[1];   // (1024,1024)
  const float* Wkv = (const float*)d_in[2];   // (1024,2048)
  const float* Wo  = (const float*)d_in[3];   // (1024,1024)
  const float* bo  = (const float*)d_in[4];   // (1024,)
  float* out = (float*)d_out;                 // (2,2048,1024) f32

  char* ws = (char*)d_ws;
  f16* xb    = (f16*)ws;  ws += (size_t)4096 * 1024 * 2;
  f16* WqkvT = (f16*)ws;  ws += (size_t)3072 * 1024 * 2;
  f16* WoT   = (f16*)ws;  ws += (size_t)1024 * 1024 * 2;
  f16* qb    = (f16*)ws;  ws += (size_t)32 * 2048 * 64 * 2;
  f16* kb    = (f16*)ws;  ws += (size_t)32 * 2048 * 64 * 2;
  f16* vtb   = (f16*)ws;  ws += (size_t)32 * 64 * 2048 * 2;
  f16* ob    = xb;  // xb dead after GEMM1; reuse

  cvt_f32_f16<<<dim3(4096), 256, 0, stream>>>(x, xb, 4096 * 1024 / 4);
  transpose3<<<dim3(64, 32, 3), dim3(32, 8), 0, stream>>>(Wq, Wkv, Wo, WqkvT, WoT);

  gemm1<<<dim3(24, 32), 256, 0, stream>>>(xb, WqkvT, qb, kb, vtb);
  attn<<<dim3(512), 256, 0, stream>>>(qb, kb, vtb, ob);
  gemm2<<<dim3(16, 32), 256, 0, stream>>>(ob, WoT, bo, out);
}